// Round 1
// baseline (13274.724 us; speedup 1.0000x reference)
//
#include <hip/hip_runtime.h>
#include <math.h>

#define NB 16
#define NC 512
#define NH 16
#define NW 64
#define NT 128
#define NV 600
#define NE 80
#define EH 256
#define DH 512
#define NSEQ 256     // NB*NH
#define GEH 1024     // 4*EH
#define GDH 2048     // 4*DH

// ---- workspace layout (float offsets) ----
#define OFF_XPRE_F 0ull          // 64*256*1024   (later aliased by embproj)
#define OFF_XPRE_B 16777216ull   // 64*256*1024
#define OFF_XT     33554432ull   // 64*256*512    (later aliased by wv_enc)
#define OFF_ENC    41943040ull   // 256*64*512
#define OFF_WENC   50331648ull   // 2*256*256*4   enc weights [dir][k][j][g]
#define OFF_WDT    50855936ull   // 848*2048      [k][gate]  (ih cols then hh cols)
#define OFF_WHT    52592640ull   // 512*512       Wh_w^T
#define OFF_WCT    52854784ull   // 1024*256      Wc_w^T
#define OFF_WOUTT  53116928ull   // 256*600       Wout_w^T
#define OFF_HA     53270528ull   // 2*256*256
#define OFF_HB     53401600ull
#define OFF_CENC   53532672ull
#define OFF_CDEC   53663744ull   // 16*512
#define OFF_CTX0   53671936ull   // 16*512
#define OFF_OPT    53680128ull   // 768*16  (rows 0..255 = O, 256..767 = h)
#define OFF_OCTT   53692416ull   // 1024*16 (rows 0..511 = h, 512..1023 = ctx)
#define OFF_GPART  53708800ull   // 6*16*2560
#define OFF_CTXP   53954560ull   // 16*16*512
#define OFF_SPART  54085632ull   // 256
#define OFF_EV     54085888ull   // 16*600
#define OFF_EVP    54095488ull   // 16*16
#define WS_FLOATS  54095744ull   // ~216.4 MB needed

__device__ __forceinline__ float sigf(float x) {
  return __builtin_amdgcn_rcpf(1.f + __expf(-x));
}
__device__ __forceinline__ float tanhfast(float x) {
  float e = __expf(2.f * x);
  return 1.f - 2.f * __builtin_amdgcn_rcpf(e + 1.f);
}

// ---------- generic transpose: src[R][C] -> dst[C][R] ----------
__global__ void k_transpose(float* __restrict__ dst, const float* __restrict__ src,
                            int R, int Cc) {
  int idx = blockIdx.x * 256 + threadIdx.x;
  if (idx >= R * Cc) return;
  int c = idx / R, r = idx - c * R;
  dst[idx] = src[(size_t)r * Cc + c];
}

// ---------- encoder recurrent weights: dst[(k*256+j)*4+g] = Whh[g*256+j][k] ----------
__global__ void k_prep_wenc(float* __restrict__ dst, const float* __restrict__ whh, int dir) {
  int idx = blockIdx.x * 256 + threadIdx.x;   // 262144
  int g = idx & 3, j = (idx >> 2) & 255, k = idx >> 10;
  dst[(size_t)dir * 262144 + idx] = whh[((size_t)(g * 256 + j)) * 256 + k];
}

// ---------- features (B,C,H,W) -> Xt[(w*256+n)*512+c] ----------
__global__ void k_buildXt(float* __restrict__ Xt, const float* __restrict__ feat) {
  __shared__ float tile[64][65];
  int n = blockIdx.x, cb = blockIdx.y * 64;
  int b = n >> 4, hh = n & 15;
  int tid = threadIdx.x;
  for (int i = 0; i < 16; ++i) {
    int c = (tid >> 6) + i * 4;
    int w = tid & 63;
    tile[c][w] = feat[(((size_t)b * NC + cb + c) * NH + hh) * NW + w];
  }
  __syncthreads();
  for (int i = 0; i < 16; ++i) {
    int w = (tid >> 6) + i * 4;
    int ci = tid & 63;
    Xt[((size_t)(w * NSEQ + n)) * NC + cb + ci] = tile[ci][w];
  }
}

// ---------- fp32 GEMM:  C[M,N] = A[M,K] @ W[N,K]^T + b1 + b2 ----------
__global__ __launch_bounds__(256) void k_gemm_nt(
    const float* __restrict__ A, const float* __restrict__ Wt,
    const float* __restrict__ bias1, const float* __restrict__ bias2,
    float* __restrict__ Cout, int M, int Nn, int K) {
  __shared__ float As[128 * 32];
  __shared__ float Bs[128 * 32];
  int tid = threadIdx.x;
  int mb = blockIdx.x * 128, nb = blockIdx.y * 128;
  int tx = tid & 15, ty = tid >> 4;
  int row0 = ty * 8, col0 = tx * 8;
  float acc[8][8];
#pragma unroll
  for (int i = 0; i < 8; ++i)
#pragma unroll
    for (int j = 0; j < 8; ++j) acc[i][j] = 0.f;
  int lm = tid >> 1, lk = (tid & 1) * 8;
  int sw = 4 * ((lm >> 3) & 7);
  int p0 = (lk + sw) & 31, p1 = (lk + 4 + sw) & 31;
  const float* Ap = A + (size_t)(mb + lm) * K + lk;
  const float* Bp = Wt + (size_t)(nb + lm) * K + lk;
  for (int k0 = 0; k0 < K; k0 += 16) {
    float4 a0 = *(const float4*)(Ap + k0);
    float4 a1 = *(const float4*)(Ap + k0 + 4);
    float4 b0 = *(const float4*)(Bp + k0);
    float4 b1 = *(const float4*)(Bp + k0 + 4);
    __syncthreads();
    *(float4*)&As[lm * 32 + p0] = a0;
    *(float4*)&As[lm * 32 + p1] = a1;
    *(float4*)&Bs[lm * 32 + p0] = b0;
    *(float4*)&Bs[lm * 32 + p1] = b1;
    __syncthreads();
#pragma unroll
    for (int kq = 0; kq < 4; ++kq) {
      float4 av[8], bv[8];
#pragma unroll
      for (int i = 0; i < 8; ++i) {
        int m = row0 + i;
        av[i] = *(float4*)&As[m * 32 + ((kq * 4 + 4 * ((m >> 3) & 7)) & 31)];
      }
#pragma unroll
      for (int j = 0; j < 8; ++j) {
        int n = col0 + j;
        bv[j] = *(float4*)&Bs[n * 32 + ((kq * 4 + 4 * ((n >> 3) & 7)) & 31)];
      }
#pragma unroll
      for (int i = 0; i < 8; ++i)
#pragma unroll
        for (int j = 0; j < 8; ++j)
          acc[i][j] += av[i].x * bv[j].x + av[i].y * bv[j].y
                     + av[i].z * bv[j].z + av[i].w * bv[j].w;
    }
  }
  float bs[8];
#pragma unroll
  for (int j = 0; j < 8; ++j) {
    float v = bias1 ? bias1[nb + col0 + j] : 0.f;
    if (bias2) v += bias2[nb + col0 + j];
    bs[j] = v;
  }
  for (int i = 0; i < 8; ++i) {
    float* cp = Cout + (size_t)(mb + row0 + i) * Nn + nb + col0;
#pragma unroll
    for (int j = 0; j < 8; ++j) cp[j] = acc[i][j] + bs[j];
  }
}

// ---------- encoder init ----------
__global__ void k_enc_init(float* __restrict__ h, float* __restrict__ c,
                           const float* __restrict__ Vh0, const float* __restrict__ Vc0) {
  int idx = blockIdx.x * 256 + threadIdx.x;   // < 131072
  int dir = idx >> 16, u = idx & 255;
  h[idx] = Vh0[dir * 256 + u];
  c[idx] = Vc0[dir * 256 + u];
}

// ---------- one encoder time step, both directions ----------
// grid (32 jc, 4 sc, 2 dir), block 256 = 64 lanes(seq) x 4 ty(2 units each)
__global__ __launch_bounds__(256) void k_enc_step(
    const float* __restrict__ hprev, float* __restrict__ hnext,
    float* __restrict__ cenc, const float* __restrict__ wenc,
    const float* __restrict__ xpreF, const float* __restrict__ xpreB,
    float* __restrict__ encout, int t) {
  __shared__ float hT[256 * 65];
  int jc = blockIdx.x, sc = blockIdx.y, dir = blockIdx.z;
  int tid = threadIdx.x;
  int lane = tid & 63;
  int tyu = __builtin_amdgcn_readfirstlane(tid >> 6);
  int dbase = dir * NSEQ + sc * 64;
  // stage h tile transposed: hT[k][s]
  for (int i = 0; i < 16; ++i) {
    int idx = tid + 256 * i;        // 4096 float4 slots
    int s = idx >> 6, k4 = (idx & 63) * 4;
    float4 v = *(const float4*)&hprev[(size_t)(dbase + s) * EH + k4];
    hT[(k4 + 0) * 65 + s] = v.x;
    hT[(k4 + 1) * 65 + s] = v.y;
    hT[(k4 + 2) * 65 + s] = v.z;
    hT[(k4 + 3) * 65 + s] = v.w;
  }
  __syncthreads();
  int j0 = jc * 8 + tyu * 2;
  const float* wp = wenc + (size_t)dir * 262144 + (size_t)j0 * 4;
  float acc0[4] = {0.f, 0.f, 0.f, 0.f}, acc1[4] = {0.f, 0.f, 0.f, 0.f};
#pragma unroll 4
  for (int k = 0; k < 256; ++k) {
    float hv = hT[k * 65 + lane];
    float4 w0 = *(const float4*)(wp + (size_t)k * 1024);
    float4 w1 = *(const float4*)(wp + (size_t)k * 1024 + 4);
    acc0[0] += w0.x * hv; acc0[1] += w0.y * hv; acc0[2] += w0.z * hv; acc0[3] += w0.w * hv;
    acc1[0] += w1.x * hv; acc1[1] += w1.y * hv; acc1[2] += w1.z * hv; acc1[3] += w1.w * hv;
  }
  int n = sc * 64 + lane;
  int w = (dir == 0) ? t : (63 - t);
  const float* xp = (dir ? xpreB : xpreF) + (size_t)w * (NSEQ * GEH) + (size_t)n * GEH;
#pragma unroll
  for (int u = 0; u < 2; ++u) {
    int j = j0 + u;
    float* ac = u ? acc1 : acc0;
    float gi_ = ac[0] + xp[j];
    float gf_ = ac[1] + xp[j + 256];
    float gg_ = ac[2] + xp[j + 512];
    float go_ = ac[3] + xp[j + 768];
    size_t ci = (size_t)(dir * NSEQ + n) * EH + j;
    float cold = cenc[ci];
    float cn = sigf(gf_) * cold + sigf(gi_) * tanhfast(gg_);
    cenc[ci] = cn;
    float hn = sigf(go_) * tanhfast(cn);
    hnext[ci] = hn;
    encout[((size_t)n * NW + w) * (2 * EH) + dir * EH + j] = hn;
  }
}

// ---------- h0/c0/ctx0 ----------
__global__ void k_conv(const float* __restrict__ hA, const float* __restrict__ cE,
                       const float* __restrict__ enc, float* __restrict__ cdec,
                       float* __restrict__ opT, float* __restrict__ ctx0) {
  int b = blockIdx.x, tid = threadIdx.x;
  for (int d = tid; d < 512; d += 256) {
    float s = 0.f;
    for (int p = 0; p < 1024; ++p) s += enc[((size_t)b * 1024 + p) * 512 + d];
    ctx0[(size_t)b * 512 + d] = s * (1.f / 1024.f);
    int dir = d >> 8, u = d & 255;
    float sh = 0.f, sc_ = 0.f;
    for (int hh = 0; hh < 16; ++hh) {
      size_t idx = ((size_t)(dir * NSEQ + b * 16 + hh)) * EH + u;
      sh += hA[idx]; sc_ += cE[idx];
    }
    cdec[(size_t)b * 512 + d] = sc_ * (1.f / 16.f);
    opT[(size_t)(256 + d) * 16 + b] = sh * (1.f / 16.f);
  }
}

// ---------- O0 ----------
__global__ void k_O0(const float* __restrict__ opT_h, const float* __restrict__ ctx0,
                     const float* __restrict__ wcT, const float* __restrict__ wcb,
                     float* __restrict__ opT_o) {
  int b = blockIdx.x, tid = threadIdx.x;
  float a = wcb[tid];
  for (int k = 0; k < 512; ++k)
    a += opT_h[(size_t)(256 + k) * 16 + b] * wcT[(size_t)k * 256 + tid];
  const float* cb = ctx0 + (size_t)b * 512;
  for (int k = 0; k < 512; ++k)
    a += cb[k] * wcT[(size_t)(512 + k) * 256 + tid];
  opT_o[(size_t)tid * 16 + b] = tanhfast(a);
}

// ---------- embedding projection for all decoder steps ----------
__global__ void k_embproj(const int* __restrict__ formulas, const float* __restrict__ emb,
                          const float* __restrict__ wdT, const float* __restrict__ b1,
                          const float* __restrict__ b2, float* __restrict__ ep) {
  int g = blockIdx.x * 256 + threadIdx.x;
  int tb = blockIdx.y;                 // t*16 + b
  int b = tb & 15, t = tb >> 4;
  int tok = formulas[b * NT + t];
  const float* ev = emb + (size_t)tok * NE;
  float a = b1[g] + b2[g];
  for (int k = 0; k < NE; ++k) a += ev[k] * wdT[(size_t)k * GDH + g];
  ep[(size_t)tb * GDH + g] = a;
}

// ---------- decoder S1: gate + linh partials ----------
__global__ __launch_bounds__(256) void k_dec_gates(
    const float* __restrict__ opT, const float* __restrict__ wdT,
    const float* __restrict__ whT, float* __restrict__ gpart) {
  int oc = blockIdx.x, kc = blockIdx.y;
  int tid = threadIdx.x;
  int k0 = kc * 128;
  float acc[16];
#pragma unroll
  for (int i = 0; i < 16; ++i) acc[i] = 0.f;
  if (oc < 8) {
    int o = oc * 256 + tid;
    const float* wp = wdT + ((size_t)(80 + k0)) * GDH + o;
    const float* sp = opT + (size_t)k0 * 16;
    for (int kk = 0; kk < 128; ++kk) {
      float w = wp[(size_t)kk * GDH];
#pragma unroll
      for (int bb = 0; bb < 16; ++bb) acc[bb] += sp[kk * 16 + bb] * w;
    }
#pragma unroll
    for (int bb = 0; bb < 16; ++bb)
      gpart[((size_t)(kc * 16 + bb)) * 2560 + o] = acc[bb];
  } else {
    if (kc >= 4) return;
    int d = (oc - 8) * 256 + tid;
    const float* wp = whT + (size_t)k0 * 512 + d;
    const float* sp = opT + (size_t)(256 + k0) * 16;
    for (int kk = 0; kk < 128; ++kk) {
      float w = wp[(size_t)kk * 512];
#pragma unroll
      for (int bb = 0; bb < 16; ++bb) acc[bb] += sp[kk * 16 + bb] * w;
    }
#pragma unroll
    for (int bb = 0; bb < 16; ++bb)
      gpart[((size_t)(kc * 16 + bb)) * 2560 + 2048 + d] = acc[bb];
  }
}

// ---------- decoder S2: attention scores + exp + partial context ----------
// grid (16 b, 16 pc); prologue of pc==0 blocks normalizes previous step's logits
__global__ __launch_bounds__(256) void k_attn(
    const float* __restrict__ gpart, const float* __restrict__ whb,
    const float* __restrict__ beta, const float* __restrict__ wvenc,
    const float* __restrict__ enc, float* __restrict__ ctxp,
    float* __restrict__ spart, const float* __restrict__ ev,
    const float* __restrict__ evp, float* __restrict__ outp, int t) {
  int b = blockIdx.x, pc = blockIdx.y;
  int tid = threadIdx.x;
  if (pc == 0 && t > 0) {
    float tot = 0.f;
#pragma unroll
    for (int i = 0; i < 10; ++i) tot += evp[b * 16 + i];
    float r = __builtin_amdgcn_rcpf(tot);
    float* orow = outp + ((size_t)b * NT + (t - 1)) * NV;
    orow[tid] = ev[b * NV + tid] * r;
    orow[tid + 256] = ev[b * NV + tid + 256] * r;
    if (tid < 88) orow[tid + 512] = ev[b * NV + tid + 512] * r;
  }
  int lane = tid & 63, wq = tid >> 6;
  __shared__ float s_lds[64];
  int d0 = lane * 8;
  float lh[8], bt[8];
#pragma unroll
  for (int jj = 0; jj < 8; ++jj) {
    int d = d0 + jj;
    float v = whb[d];
#pragma unroll
    for (int kc = 0; kc < 4; ++kc)
      v += gpart[((size_t)(kc * 16 + b)) * 2560 + 2048 + d];
    lh[jj] = v;
    bt[jj] = beta[d];
  }
  for (int pi = 0; pi < 16; ++pi) {
    int p = pc * 64 + wq * 16 + pi;
    const float* wvp = wvenc + ((size_t)b * 1024 + p) * 512 + d0;
    float e = 0.f;
#pragma unroll
    for (int jj = 0; jj < 8; ++jj) e += bt[jj] * tanhfast(lh[jj] + wvp[jj]);
#pragma unroll
    for (int m = 1; m < 64; m <<= 1) e += __shfl_xor(e, m, 64);
    if (lane == 0) s_lds[wq * 16 + pi] = __expf(e);   // |e|<=5.2, safe
  }
  __syncthreads();
  float a0 = 0.f, a1 = 0.f;
  for (int p = 0; p < 64; ++p) {
    float sp = s_lds[p];
    const float* er = enc + ((size_t)b * 1024 + pc * 64 + p) * 512;
    a0 += sp * er[tid];
    a1 += sp * er[tid + 256];
  }
  ctxp[((size_t)(b * 16 + pc)) * 512 + tid] = a0;
  ctxp[((size_t)(b * 16 + pc)) * 512 + tid + 256] = a1;
  if (tid == 0) {
    float s = 0.f;
#pragma unroll
    for (int p = 0; p < 64; ++p) s += s_lds[p];
    spart[b * 16 + pc] = s;
  }
}

// ---------- decoder S3: cell update + context reduce ----------
__global__ void k_dec_cell(const float* __restrict__ gpart, const float* __restrict__ ep,
                           const float* __restrict__ ctxp, const float* __restrict__ spart,
                           float* __restrict__ cdec, float* __restrict__ opT,
                           float* __restrict__ octT, int t) {
  int b = blockIdx.x, tid = threadIdx.x;
  float Ssum = 0.f;
#pragma unroll
  for (int pc = 0; pc < 16; ++pc) Ssum += spart[b * 16 + pc];
  float rS = __builtin_amdgcn_rcpf(Ssum);
  for (int d = tid; d < 512; d += 256) {
    float s = 0.f;
#pragma unroll
    for (int pc = 0; pc < 16; ++pc)
      s += ctxp[((size_t)(b * 16 + pc)) * 512 + d];
    octT[(size_t)(512 + d) * 16 + b] = s * rS;
  }
  for (int j = tid; j < 512; j += 256) {
    float g[4];
#pragma unroll
    for (int gi = 0; gi < 4; ++gi) {
      float v = ep[((size_t)t * 16 + b) * GDH + gi * 512 + j];
#pragma unroll
      for (int kc = 0; kc < 6; ++kc)
        v += gpart[((size_t)(kc * 16 + b)) * 2560 + gi * 512 + j];
      g[gi] = v;
    }
    size_t ci = (size_t)b * 512 + j;
    float cn = sigf(g[1]) * cdec[ci] + sigf(g[0]) * tanhfast(g[2]);
    cdec[ci] = cn;
    float hn = sigf(g[3]) * tanhfast(cn);
    opT[(size_t)(256 + j) * 16 + b] = hn;
    octT[(size_t)j * 16 + b] = hn;
  }
}

// ---------- decoder S4: O_t = tanh([h;ctx] @ Wc^T + b) ----------
// grid 8 (j-chunks of 32); block 256 = 4 waves (k-quarters) x (32 j x 2 b-halves)
__global__ __launch_bounds__(256) void k_dec_O(
    const float* __restrict__ octT, const float* __restrict__ wcT,
    const float* __restrict__ wcb, float* __restrict__ opT) {
  int jc = blockIdx.x, tid = threadIdx.x;
  int lane = tid & 63, wq = tid >> 6;
  int jl = lane & 31, bh = lane >> 5;
  int j = jc * 32 + jl;
  __shared__ float part[4][32][16];
  float acc[8] = {0.f, 0.f, 0.f, 0.f, 0.f, 0.f, 0.f, 0.f};
  int k0 = wq * 256;
  for (int k = k0; k < k0 + 256; ++k) {
    float w = wcT[(size_t)k * 256 + j];
    const float4* op = (const float4*)&octT[(size_t)k * 16 + bh * 8];
    float4 o0 = op[0], o1 = op[1];
    acc[0] += w * o0.x; acc[1] += w * o0.y; acc[2] += w * o0.z; acc[3] += w * o0.w;
    acc[4] += w * o1.x; acc[5] += w * o1.y; acc[6] += w * o1.z; acc[7] += w * o1.w;
  }
#pragma unroll
  for (int i = 0; i < 8; ++i) part[wq][jl][bh * 8 + i] = acc[i];
  __syncthreads();
  for (int o = tid; o < 512; o += 256) {
    int jj = o >> 4, bb = o & 15;
    float s = part[0][jj][bb] + part[1][jj][bb] + part[2][jj][bb] + part[3][jj][bb];
    float O = tanhfast(s + wcb[jc * 32 + jj]);
    opT[(size_t)(jc * 32 + jj) * 16 + bb] = O;
  }
}

// ---------- decoder S5: logits -> exp + per-chunk sums ----------
// grid 10 (v-chunks of 64); block 256 = 64 v-lanes x 4 b-quads
__global__ __launch_bounds__(256) void k_dec_logits(
    const float* __restrict__ opT, const float* __restrict__ woutT,
    const float* __restrict__ woutb, float* __restrict__ ev,
    float* __restrict__ evp) {
  int vc = blockIdx.x, tid = threadIdx.x;
  int lane = tid & 63;
  int tyu = __builtin_amdgcn_readfirstlane(tid >> 6);
  int v = vc * 64 + lane;
  bool valid = v < NV;
  int vl = valid ? v : (NV - 1);
  float acc[4] = {0.f, 0.f, 0.f, 0.f};
  for (int k = 0; k < 256; ++k) {
    float w = woutT[(size_t)k * NV + vl];
    const float4* op = (const float4*)&opT[(size_t)k * 16 + tyu * 4];
    float4 o4 = *op;
    acc[0] += w * o4.x; acc[1] += w * o4.y; acc[2] += w * o4.z; acc[3] += w * o4.w;
  }
  float bs = woutb[vl];
  float e[4];
#pragma unroll
  for (int i = 0; i < 4; ++i) e[i] = valid ? __expf(acc[i] + bs) : 0.f;
  if (valid) {
#pragma unroll
    for (int i = 0; i < 4; ++i)
      ev[(size_t)(tyu * 4 + i) * NV + v] = e[i];
  }
#pragma unroll
  for (int i = 0; i < 4; ++i) {
    float s = e[i];
#pragma unroll
    for (int m = 1; m < 64; m <<= 1) s += __shfl_xor(s, m, 64);
    if (lane == 0) evp[(size_t)(tyu * 4 + i) * 16 + vc] = s;
  }
}

// ---------- normalize final step's logits ----------
__global__ void k_norm(const float* __restrict__ ev, const float* __restrict__ evp,
                       float* __restrict__ outp, int t) {
  int b = blockIdx.x, tid = threadIdx.x;
  float tot = 0.f;
#pragma unroll
  for (int i = 0; i < 10; ++i) tot += evp[b * 16 + i];
  float r = __builtin_amdgcn_rcpf(tot);
  float* orow = outp + ((size_t)b * NT + t) * NV;
  orow[tid] = ev[b * NV + tid] * r;
  orow[tid + 256] = ev[b * NV + tid + 256] * r;
  if (tid < 88) orow[tid + 512] = ev[b * NV + tid + 512] * r;
}

// ---------- argmax over V per (b,t) ----------
__global__ void k_argmax(const float* __restrict__ outp, float* __restrict__ tgt) {
  int bt = blockIdx.x;
  int lane = threadIdx.x;    // 64
  const float* row = outp + (size_t)bt * NV;
  float bv = -1.f;
  int bi = 0;
  for (int v = lane; v < NV; v += 64) {
    float x = row[v];
    if (x > bv) { bv = x; bi = v; }
  }
#pragma unroll
  for (int m = 1; m < 64; m <<= 1) {
    float ov = __shfl_xor(bv, m, 64);
    int oi = __shfl_xor(bi, m, 64);
    if (ov > bv || (ov == bv && oi < bi)) { bv = ov; bi = oi; }
  }
  if (lane == 0) tgt[bt] = (float)bi;
}

extern "C" void kernel_launch(void* const* d_in, const int* in_sizes, int n_in,
                              void* d_out, int out_size, void* d_ws, size_t ws_size,
                              hipStream_t stream) {
  (void)in_sizes; (void)n_in; (void)out_size;
  if (ws_size < WS_FLOATS * sizeof(float)) return;   // need ~216.4 MB scratch

  const float* feat     = (const float*)d_in[0];
  const int*   formulas = (const int*)d_in[1];
  const float* Wih_f    = (const float*)d_in[2];
  const float* Whh_f    = (const float*)d_in[3];
  const float* bih_f    = (const float*)d_in[4];
  const float* bhh_f    = (const float*)d_in[5];
  const float* Wih_b    = (const float*)d_in[6];
  const float* Whh_b    = (const float*)d_in[7];
  const float* bih_b    = (const float*)d_in[8];
  const float* bhh_b    = (const float*)d_in[9];
  const float* emb      = (const float*)d_in[10];
  const float* Wc_w     = (const float*)d_in[11];
  const float* Wc_b     = (const float*)d_in[12];
  const float* Wout_w   = (const float*)d_in[13];
  const float* Wout_b   = (const float*)d_in[14];
  const float* Vh0      = (const float*)d_in[15];
  const float* Vc0      = (const float*)d_in[16];
  const float* beta     = (const float*)d_in[17];
  const float* Wh_w     = (const float*)d_in[18];
  const float* Wh_b     = (const float*)d_in[19];
  const float* Wv_w     = (const float*)d_in[20];
  const float* Wv_b     = (const float*)d_in[21];
  const float* Wdec_ih  = (const float*)d_in[22];
  const float* Wdec_hh  = (const float*)d_in[23];
  const float* bdec_ih  = (const float*)d_in[24];
  const float* bdec_hh  = (const float*)d_in[25];

  float* ws = (float*)d_ws;
  float* xpreF  = ws + OFF_XPRE_F;
  float* xpreB  = ws + OFF_XPRE_B;
  float* xt     = ws + OFF_XT;
  float* encout = ws + OFF_ENC;
  float* wenc   = ws + OFF_WENC;
  float* wdT    = ws + OFF_WDT;
  float* whT    = ws + OFF_WHT;
  float* wcT    = ws + OFF_WCT;
  float* woutT  = ws + OFF_WOUTT;
  float* hA     = ws + OFF_HA;
  float* hB     = ws + OFF_HB;
  float* cenc   = ws + OFF_CENC;
  float* cdec   = ws + OFF_CDEC;
  float* ctx0   = ws + OFF_CTX0;
  float* opT    = ws + OFF_OPT;
  float* octT   = ws + OFF_OCTT;
  float* gpart  = ws + OFF_GPART;
  float* ctxp   = ws + OFF_CTXP;
  float* spart  = ws + OFF_SPART;
  float* ev     = ws + OFF_EV;
  float* evp    = ws + OFF_EVP;
  float* embproj = xpreF;   // alias: written after encoder finishes with xpreF
  float* wvenc   = xt;      // alias: written after GEMMs finish with xt

  float* out_logits = (float*)d_out;
  float* out_tgt    = out_logits + (size_t)NB * NT * NV;

  // ---- prep ----
  k_transpose<<<(2048 * 336 + 255) / 256, 256, 0, stream>>>(wdT, Wdec_ih, 2048, 336);
  k_transpose<<<(2048 * 512 + 255) / 256, 256, 0, stream>>>(wdT + 336 * 2048, Wdec_hh, 2048, 512);
  k_transpose<<<(512 * 512 + 255) / 256, 256, 0, stream>>>(whT, Wh_w, 512, 512);
  k_transpose<<<(256 * 1024 + 255) / 256, 256, 0, stream>>>(wcT, Wc_w, 256, 1024);
  k_transpose<<<(600 * 256 + 255) / 256, 256, 0, stream>>>(woutT, Wout_w, 600, 256);
  k_prep_wenc<<<1024, 256, 0, stream>>>(wenc, Whh_f, 0);
  k_prep_wenc<<<1024, 256, 0, stream>>>(wenc, Whh_b, 1);
  k_buildXt<<<dim3(256, 8), 256, 0, stream>>>(xt, feat);
  k_gemm_nt<<<dim3(128, 8), 256, 0, stream>>>(xt, Wih_f, bih_f, bhh_f, xpreF, 16384, 1024, 512);
  k_gemm_nt<<<dim3(128, 8), 256, 0, stream>>>(xt, Wih_b, bih_b, bhh_b, xpreB, 16384, 1024, 512);

  // ---- encoder ----
  k_enc_init<<<512, 256, 0, stream>>>(hA, cenc, Vh0, Vc0);
  for (int t = 0; t < 64; ++t) {
    const float* hp = (t & 1) ? hB : hA;
    float* hn = (t & 1) ? hA : hB;
    k_enc_step<<<dim3(32, 4, 2), 256, 0, stream>>>(hp, hn, cenc, wenc, xpreF, xpreB, encout, t);
  }
  // final h/c in hA / cenc
  k_gemm_nt<<<dim3(128, 4), 256, 0, stream>>>(encout, Wv_w, Wv_b, nullptr, wvenc, 16384, 512, 512);
  k_conv<<<16, 256, 0, stream>>>(hA, cenc, encout, cdec, opT, ctx0);
  k_O0<<<16, 256, 0, stream>>>(opT, ctx0, wcT, Wc_b, opT);
  k_embproj<<<dim3(8, 2048), 256, 0, stream>>>(formulas, emb, wdT, bdec_ih, bdec_hh, embproj);

  // ---- decoder ----
  for (int t = 0; t < NT; ++t) {
    k_dec_gates<<<dim3(10, 6), 256, 0, stream>>>(opT, wdT, whT, gpart);
    k_attn<<<dim3(16, 16), 256, 0, stream>>>(gpart, Wh_b, beta, wvenc, encout,
                                             ctxp, spart, ev, evp, out_logits, t);
    k_dec_cell<<<16, 256, 0, stream>>>(gpart, embproj, ctxp, spart, cdec, opT, octT, t);
    k_dec_O<<<8, 256, 0, stream>>>(octT, wcT, Wc_b, opT);
    k_dec_logits<<<10, 256, 0, stream>>>(opT, woutT, Wout_b, ev, evp);
  }
  k_norm<<<16, 256, 0, stream>>>(ev, evp, out_logits, NT - 1);
  k_argmax<<<NB * NT, 64, 0, stream>>>(out_logits, out_tgt);
}

// Round 3
// 10976.941 us; speedup vs baseline: 1.2093x; 1.2093x over previous
//
#include <hip/hip_runtime.h>
#include <math.h>

#define NB 16
#define NC 512
#define NH 16
#define NW 64
#define NT 128
#define NV 600
#define NE 80
#define EH 256
#define DH 512
#define NSEQ 256     // NB*NH
#define GEH 1024     // 4*EH
#define GDH 2048     // 4*DH

// ---- workspace layout (float offsets) ----
#define OFF_XPRE_F 0ull          // 64*256*1024   (later aliased by embproj)
#define OFF_XPRE_B 16777216ull   // 64*256*1024   (later aliased by decoder scratch)
#define OFF_XT     33554432ull   // 64*256*512    (later aliased by wv_enc)
#define OFF_ENC    41943040ull   // 256*64*512
#define OFF_WENC   50331648ull   // 2*256*256*4
#define OFF_WDT    50855936ull   // 848*2048
#define OFF_WHT    52592640ull   // 512*512
#define OFF_WCT    52854784ull   // 1024*256
#define OFF_WOUTT  53116928ull   // 256*600
#define OFF_HA     53270528ull
#define OFF_HB     53401600ull
#define OFF_CENC   53532672ull
#define OFF_CDEC   53663744ull   // 16*512
#define OFF_CTX0   53671936ull   // 16*512
#define OFF_OKT    53680128ull   // 768*16 (rows 0..255=O, 256..767=h)
#define OFF_OCTT   53692416ull   // 1024*16 (rows 0..511=h, 512..1023=ctx)
#define WS_FLOATS  53708800ull   // ~214.8 MB

__device__ __forceinline__ float sigf(float x) {
  return __builtin_amdgcn_rcpf(1.f + __expf(-x));
}
__device__ __forceinline__ float tanhfast(float x) {
  float e = __expf(2.f * x);
  return 1.f - 2.f * __builtin_amdgcn_rcpf(e + 1.f);
}

// ---------- generic transpose ----------
__global__ void k_transpose(float* __restrict__ dst, const float* __restrict__ src,
                            int R, int Cc) {
  int idx = blockIdx.x * 256 + threadIdx.x;
  if (idx >= R * Cc) return;
  int c = idx / R, r = idx - c * R;
  dst[idx] = src[(size_t)r * Cc + c];
}

__global__ void k_prep_wenc(float* __restrict__ dst, const float* __restrict__ whh, int dir) {
  int idx = blockIdx.x * 256 + threadIdx.x;
  int g = idx & 3, j = (idx >> 2) & 255, k = idx >> 10;
  dst[(size_t)dir * 262144 + idx] = whh[((size_t)(g * 256 + j)) * 256 + k];
}

__global__ void k_buildXt(float* __restrict__ Xt, const float* __restrict__ feat) {
  __shared__ float tile[64][65];
  int n = blockIdx.x, cb = blockIdx.y * 64;
  int b = n >> 4, hh = n & 15;
  int tid = threadIdx.x;
  for (int i = 0; i < 16; ++i) {
    int c = (tid >> 6) + i * 4;
    int w = tid & 63;
    tile[c][w] = feat[(((size_t)b * NC + cb + c) * NH + hh) * NW + w];
  }
  __syncthreads();
  for (int i = 0; i < 16; ++i) {
    int w = (tid >> 6) + i * 4;
    int ci = tid & 63;
    Xt[((size_t)(w * NSEQ + n)) * NC + cb + ci] = tile[ci][w];
  }
}

// ---------- fp32 GEMM ----------
__global__ __launch_bounds__(256) void k_gemm_nt(
    const float* __restrict__ A, const float* __restrict__ Wt,
    const float* __restrict__ bias1, const float* __restrict__ bias2,
    float* __restrict__ Cout, int M, int Nn, int K) {
  __shared__ float As[128 * 32];
  __shared__ float Bs[128 * 32];
  int tid = threadIdx.x;
  int mb = blockIdx.x * 128, nb = blockIdx.y * 128;
  int tx = tid & 15, ty = tid >> 4;
  int row0 = ty * 8, col0 = tx * 8;
  float acc[8][8];
#pragma unroll
  for (int i = 0; i < 8; ++i)
#pragma unroll
    for (int j = 0; j < 8; ++j) acc[i][j] = 0.f;
  int lm = tid >> 1, lk = (tid & 1) * 8;
  int sw = 4 * ((lm >> 3) & 7);
  int p0 = (lk + sw) & 31, p1 = (lk + 4 + sw) & 31;
  const float* Ap = A + (size_t)(mb + lm) * K + lk;
  const float* Bp = Wt + (size_t)(nb + lm) * K + lk;
  for (int k0 = 0; k0 < K; k0 += 16) {
    float4 a0 = *(const float4*)(Ap + k0);
    float4 a1 = *(const float4*)(Ap + k0 + 4);
    float4 b0 = *(const float4*)(Bp + k0);
    float4 b1 = *(const float4*)(Bp + k0 + 4);
    __syncthreads();
    *(float4*)&As[lm * 32 + p0] = a0;
    *(float4*)&As[lm * 32 + p1] = a1;
    *(float4*)&Bs[lm * 32 + p0] = b0;
    *(float4*)&Bs[lm * 32 + p1] = b1;
    __syncthreads();
#pragma unroll
    for (int kq = 0; kq < 4; ++kq) {
      float4 av[8], bv[8];
#pragma unroll
      for (int i = 0; i < 8; ++i) {
        int m = row0 + i;
        av[i] = *(float4*)&As[m * 32 + ((kq * 4 + 4 * ((m >> 3) & 7)) & 31)];
      }
#pragma unroll
      for (int j = 0; j < 8; ++j) {
        int n = col0 + j;
        bv[j] = *(float4*)&Bs[n * 32 + ((kq * 4 + 4 * ((n >> 3) & 7)) & 31)];
      }
#pragma unroll
      for (int i = 0; i < 8; ++i)
#pragma unroll
        for (int j = 0; j < 8; ++j)
          acc[i][j] += av[i].x * bv[j].x + av[i].y * bv[j].y
                     + av[i].z * bv[j].z + av[i].w * bv[j].w;
    }
  }
  float bs[8];
#pragma unroll
  for (int j = 0; j < 8; ++j) {
    float v = bias1 ? bias1[nb + col0 + j] : 0.f;
    if (bias2) v += bias2[nb + col0 + j];
    bs[j] = v;
  }
  for (int i = 0; i < 8; ++i) {
    float* cp = Cout + (size_t)(mb + row0 + i) * Nn + nb + col0;
#pragma unroll
    for (int j = 0; j < 8; ++j) cp[j] = acc[i][j] + bs[j];
  }
}

__global__ void k_enc_init(float* __restrict__ h, float* __restrict__ c,
                           const float* __restrict__ Vh0, const float* __restrict__ Vc0) {
  int idx = blockIdx.x * 256 + threadIdx.x;
  int dir = idx >> 16, u = idx & 255;
  h[idx] = Vh0[dir * 256 + u];
  c[idx] = Vc0[dir * 256 + u];
}

// ---------- one encoder time step, both directions ----------
__global__ __launch_bounds__(256) void k_enc_step(
    const float* __restrict__ hprev, float* __restrict__ hnext,
    float* __restrict__ cenc, const float* __restrict__ wenc,
    const float* __restrict__ xpreF, const float* __restrict__ xpreB,
    float* __restrict__ encout, int t) {
  __shared__ float hT[256 * 65];
  int jc = blockIdx.x, sc = blockIdx.y, dir = blockIdx.z;
  int tid = threadIdx.x;
  int lane = tid & 63;
  int tyu = __builtin_amdgcn_readfirstlane(tid >> 6);
  int dbase = dir * NSEQ + sc * 64;
  for (int i = 0; i < 16; ++i) {
    int idx = tid + 256 * i;
    int s = idx >> 6, k4 = (idx & 63) * 4;
    float4 v = *(const float4*)&hprev[(size_t)(dbase + s) * EH + k4];
    hT[(k4 + 0) * 65 + s] = v.x;
    hT[(k4 + 1) * 65 + s] = v.y;
    hT[(k4 + 2) * 65 + s] = v.z;
    hT[(k4 + 3) * 65 + s] = v.w;
  }
  __syncthreads();
  int j0 = jc * 8 + tyu * 2;
  const float* wp = wenc + (size_t)dir * 262144 + (size_t)j0 * 4;
  float acc0[4] = {0.f, 0.f, 0.f, 0.f}, acc1[4] = {0.f, 0.f, 0.f, 0.f};
#pragma unroll 4
  for (int k = 0; k < 256; ++k) {
    float hv = hT[k * 65 + lane];
    float4 w0 = *(const float4*)(wp + (size_t)k * 1024);
    float4 w1 = *(const float4*)(wp + (size_t)k * 1024 + 4);
    acc0[0] += w0.x * hv; acc0[1] += w0.y * hv; acc0[2] += w0.z * hv; acc0[3] += w0.w * hv;
    acc1[0] += w1.x * hv; acc1[1] += w1.y * hv; acc1[2] += w1.z * hv; acc1[3] += w1.w * hv;
  }
  int n = sc * 64 + lane;
  int w = (dir == 0) ? t : (63 - t);
  const float* xp = (dir ? xpreB : xpreF) + (size_t)w * (NSEQ * GEH) + (size_t)n * GEH;
#pragma unroll
  for (int u = 0; u < 2; ++u) {
    int j = j0 + u;
    float* ac = u ? acc1 : acc0;
    float gi_ = ac[0] + xp[j];
    float gf_ = ac[1] + xp[j + 256];
    float gg_ = ac[2] + xp[j + 512];
    float go_ = ac[3] + xp[j + 768];
    size_t ci = (size_t)(dir * NSEQ + n) * EH + j;
    float cold = cenc[ci];
    float cn = sigf(gf_) * cold + sigf(gi_) * tanhfast(gg_);
    cenc[ci] = cn;
    float hn = sigf(go_) * tanhfast(cn);
    hnext[ci] = hn;
    encout[((size_t)n * NW + w) * (2 * EH) + dir * EH + j] = hn;
  }
}

__global__ void k_conv(const float* __restrict__ hA, const float* __restrict__ cE,
                       const float* __restrict__ enc, float* __restrict__ cdec,
                       float* __restrict__ okT, float* __restrict__ ctx0) {
  int b = blockIdx.x, tid = threadIdx.x;
  for (int d = tid; d < 512; d += 256) {
    float s = 0.f;
    for (int p = 0; p < 1024; ++p) s += enc[((size_t)b * 1024 + p) * 512 + d];
    ctx0[(size_t)b * 512 + d] = s * (1.f / 1024.f);
    int dir = d >> 8, u = d & 255;
    float sh = 0.f, sc_ = 0.f;
    for (int hh = 0; hh < 16; ++hh) {
      size_t idx = ((size_t)(dir * NSEQ + b * 16 + hh)) * EH + u;
      sh += hA[idx]; sc_ += cE[idx];
    }
    cdec[(size_t)b * 512 + d] = sc_ * (1.f / 16.f);
    okT[(size_t)(256 + d) * 16 + b] = sh * (1.f / 16.f);
  }
}

// ---------- O0 + lin_h(h0) ----------
__global__ void k_O0v2(const float* __restrict__ okT, const float* __restrict__ ctx0,
                       const float* __restrict__ wcT, const float* __restrict__ wcb,
                       const float* __restrict__ whT, const float* __restrict__ whb,
                       float* __restrict__ okT_o, float* __restrict__ linh) {
  int b = blockIdx.x, tid = threadIdx.x;
  float a = wcb[tid];
  for (int k = 0; k < 512; ++k)
    a += okT[(size_t)(256 + k) * 16 + b] * wcT[(size_t)k * 256 + tid];
  const float* cb = ctx0 + (size_t)b * 512;
  for (int k = 0; k < 512; ++k)
    a += cb[k] * wcT[(size_t)(512 + k) * 256 + tid];
  okT_o[(size_t)tid * 16 + b] = tanhfast(a);
  for (int d = tid; d < 512; d += 256) {
    float v = whb[d];
    for (int k = 0; k < 512; ++k)
      v += okT[(size_t)(256 + k) * 16 + b] * whT[(size_t)k * 512 + d];
    linh[(size_t)b * 512 + d] = v;
  }
}

__global__ void k_embproj(const int* __restrict__ formulas, const float* __restrict__ emb,
                          const float* __restrict__ wdT, const float* __restrict__ b1,
                          const float* __restrict__ b2, float* __restrict__ ep) {
  int g = blockIdx.x * 256 + threadIdx.x;
  int tb = blockIdx.y;
  int b = tb & 15, t = tb >> 4;
  int tok = formulas[b * NT + t];
  const float* ev = emb + (size_t)tok * NE;
  float a = b1[g] + b2[g];
  for (int k = 0; k < NE; ++k) a += ev[k] * wdT[(size_t)k * GDH + g];
  ep[(size_t)tb * GDH + g] = a;
}

// ---------- logits helper (exp + per-chunk sums) ----------
__device__ __forceinline__ void logits_block(
    int vc, int lane, int wq, const float* __restrict__ okT,
    const float* __restrict__ woutT, const float* __restrict__ woutb,
    float* __restrict__ ev, float* __restrict__ evp) {
  int v = vc * 64 + lane;
  bool valid = v < NV;
  int vl = valid ? v : (NV - 1);
  float acc[4] = {0.f, 0.f, 0.f, 0.f};
  for (int k = 0; k < 256; ++k) {
    float w = woutT[(size_t)k * NV + vl];
    float4 o4 = *(const float4*)&okT[(size_t)k * 16 + wq * 4];
    acc[0] += w * o4.x; acc[1] += w * o4.y; acc[2] += w * o4.z; acc[3] += w * o4.w;
  }
  float bs = woutb[vl];
#pragma unroll
  for (int i = 0; i < 4; ++i) {
    float e = valid ? __expf(acc[i] + bs) : 0.f;
    if (valid) ev[(size_t)(wq * 4 + i) * NV + v] = e;
    float s = e;
#pragma unroll
    for (int m = 1; m < 64; m <<= 1) s += __shfl_xor(s, m, 64);
    if (lane == 0) evp[(wq * 4 + i) * 16 + vc] = s;
  }
}

__device__ __forceinline__ void norm_block(
    int b, int tid, const float* __restrict__ ev, const float* __restrict__ evp,
    float* __restrict__ outp, int t) {
  float tot = 0.f;
#pragma unroll
  for (int i = 0; i < 10; ++i) tot += evp[b * 16 + i];
  float r = __builtin_amdgcn_rcpf(tot);
  float* orow = outp + ((size_t)b * NT + t) * NV;
  orow[tid] = ev[b * NV + tid] * r;
  orow[tid + 256] = ev[b * NV + tid + 256] * r;
  if (tid < 88) orow[tid + 512] = ev[b * NV + tid + 512] * r;
}

// ---------- decoder K1: gate partials + lazy logits(t-1) + attention ----------
// grid 256, block 256
__global__ __launch_bounds__(256) void k_dec1(
    const float* __restrict__ okT, const float* __restrict__ wdT,
    const float* __restrict__ woutT, const float* __restrict__ woutb,
    const float* __restrict__ linh, const float* __restrict__ beta,
    const float* __restrict__ wvenc, const float* __restrict__ enc,
    float* __restrict__ gpart, float* __restrict__ ctxp,
    float* __restrict__ spart, float* __restrict__ ev, float* __restrict__ evp,
    int t) {
  __shared__ float smem[64];
  int bid = blockIdx.x, tid = threadIdx.x;
  int lane = tid & 63, wq = tid >> 6;

  if (bid < 96) {
    // gate partials: oc = bid/12 (8 o-chunks of 256), kc = bid%12 (12 k-chunks of 64)
    int oc = bid / 12, kc = bid - oc * 12;
    int o = oc * 256 + tid, k0 = kc * 64;
    const float* wp = wdT + (size_t)(80 + k0) * GDH + o;
    const float* sp = okT + (size_t)k0 * 16;
    float acc[16];
#pragma unroll
    for (int i = 0; i < 16; ++i) acc[i] = 0.f;
    for (int kk = 0; kk < 64; ++kk) {
      float w = wp[(size_t)kk * GDH];
#pragma unroll
      for (int bb = 0; bb < 16; ++bb) acc[bb] += sp[kk * 16 + bb] * w;
    }
#pragma unroll
    for (int bb = 0; bb < 16; ++bb)
      gpart[((size_t)(kc * 16 + bb)) * GDH + o] = acc[bb];
  } else if (bid < 106) {
    if (t > 0) logits_block(bid - 96, lane, wq, okT, woutT, woutb, ev, evp);
  }

  // attention: every block does one (b, pc) tile
  {
    int b = bid >> 4, pc = bid & 15;
    int d0 = lane * 8;
    float lh[8], bt[8];
    {
      const float* lp = linh + (size_t)b * 512 + d0;
#pragma unroll
      for (int jj = 0; jj < 8; ++jj) { lh[jj] = lp[jj]; bt[jj] = beta[d0 + jj]; }
    }
    for (int pi = 0; pi < 16; ++pi) {
      int p = pc * 64 + wq * 16 + pi;
      const float* wvp = wvenc + ((size_t)(b * 1024 + p)) * 512 + d0;
      float e = 0.f;
#pragma unroll
      for (int jj = 0; jj < 8; ++jj) e += bt[jj] * tanhfast(lh[jj] + wvp[jj]);
#pragma unroll
      for (int m = 1; m < 64; m <<= 1) e += __shfl_xor(e, m, 64);
      if (lane == 0) smem[wq * 16 + pi] = __expf(e);   // |e|<=5.2, safe without max-sub
    }
    __syncthreads();
    float a0 = 0.f, a1 = 0.f;
    for (int p = 0; p < 64; ++p) {
      float s = smem[p];
      const float* er = enc + ((size_t)(b * 1024 + pc * 64 + p)) * 512;
      a0 += s * er[tid];
      a1 += s * er[tid + 256];
    }
    ctxp[((size_t)(b * 16 + pc)) * 512 + tid] = a0;
    ctxp[((size_t)(b * 16 + pc)) * 512 + tid + 256] = a1;
    if (tid == 0) {
      float s = 0.f;
#pragma unroll
      for (int p = 0; p < 64; ++p) s += smem[p];
      spart[b * 16 + pc] = s;
    }
  }
}

// ---------- decoder K2a: context reduce + cell + normalize logits(t-1) ----------
// grid 16, block 256
__global__ __launch_bounds__(256) void k_dec2a(
    const float* __restrict__ gpart, const float* __restrict__ ep,
    const float* __restrict__ ctxp, const float* __restrict__ spart,
    const float* __restrict__ ev, const float* __restrict__ evp,
    float* __restrict__ cdec, float* __restrict__ okT, float* __restrict__ octT,
    float* __restrict__ outp, int t) {
  int b = blockIdx.x, tid = threadIdx.x;
  float Ssum = 0.f;
#pragma unroll
  for (int pc = 0; pc < 16; ++pc) Ssum += spart[b * 16 + pc];
  float rS = __builtin_amdgcn_rcpf(Ssum);
  for (int d = tid; d < 512; d += 256) {
    float s = 0.f;
#pragma unroll
    for (int pc = 0; pc < 16; ++pc) s += ctxp[((size_t)(b * 16 + pc)) * 512 + d];
    octT[(size_t)(512 + d) * 16 + b] = s * rS;
  }
  for (int j = tid; j < 512; j += 256) {
    float g4[4];
#pragma unroll
    for (int gi = 0; gi < 4; ++gi) {
      float v = ep[((size_t)(t * 16 + b)) * GDH + gi * 512 + j];
#pragma unroll
      for (int kc = 0; kc < 12; ++kc)
        v += gpart[((size_t)(kc * 16 + b)) * GDH + gi * 512 + j];
      g4[gi] = v;
    }
    size_t ci = (size_t)b * 512 + j;
    float cn = sigf(g4[1]) * cdec[ci] + sigf(g4[0]) * tanhfast(g4[2]);
    cdec[ci] = cn;
    float hn = sigf(g4[3]) * tanhfast(cn);
    okT[(size_t)(256 + j) * 16 + b] = hn;
    octT[(size_t)j * 16 + b] = hn;
  }
  if (t > 0) norm_block(b, tid, ev, evp, outp, t - 1);
}

// ---------- decoder K2b: O_t GEMV (8 blocks) + lin_h GEMV (16 blocks) ----------
// block 256 = 4 waves (k-split) x 64 lanes (32 j x 2 b-halves)
__global__ __launch_bounds__(256) void k_dec2b(
    const float* __restrict__ octT, const float* __restrict__ wcT,
    const float* __restrict__ wcb, const float* __restrict__ whT,
    const float* __restrict__ whb, float* __restrict__ okT,
    float* __restrict__ linh) {
  __shared__ float part[4][32][16];
  int bid = blockIdx.x, tid = threadIdx.x;
  int lane = tid & 63, wq = tid >> 6;
  int jl = lane & 31, bh = lane >> 5;
  float acc[8] = {0.f, 0.f, 0.f, 0.f, 0.f, 0.f, 0.f, 0.f};
  if (bid < 8) {
    int j = bid * 32 + jl;
    int k0 = wq * 256;
    for (int k = k0; k < k0 + 256; ++k) {
      float w = wcT[(size_t)k * 256 + j];
      const float4* op = (const float4*)&octT[(size_t)k * 16 + bh * 8];
      float4 o0 = op[0], o1 = op[1];
      acc[0] += w * o0.x; acc[1] += w * o0.y; acc[2] += w * o0.z; acc[3] += w * o0.w;
      acc[4] += w * o1.x; acc[5] += w * o1.y; acc[6] += w * o1.z; acc[7] += w * o1.w;
    }
#pragma unroll
    for (int i = 0; i < 8; ++i) part[wq][jl][bh * 8 + i] = acc[i];
    __syncthreads();
    for (int o = tid; o < 512; o += 256) {
      int jj = o >> 4, bb = o & 15;
      float s = part[0][jj][bb] + part[1][jj][bb] + part[2][jj][bb] + part[3][jj][bb];
      okT[(size_t)(bid * 32 + jj) * 16 + bb] = tanhfast(s + wcb[bid * 32 + jj]);
    }
  } else {
    int idx = bid - 8;                  // 0..15
    int j = idx * 32 + jl;              // 0..511
    int k0 = wq * 128;
    for (int k = k0; k < k0 + 128; ++k) {
      float w = whT[(size_t)k * 512 + j];
      const float4* op = (const float4*)&octT[(size_t)k * 16 + bh * 8];
      float4 o0 = op[0], o1 = op[1];
      acc[0] += w * o0.x; acc[1] += w * o0.y; acc[2] += w * o0.z; acc[3] += w * o0.w;
      acc[4] += w * o1.x; acc[5] += w * o1.y; acc[6] += w * o1.z; acc[7] += w * o1.w;
    }
#pragma unroll
    for (int i = 0; i < 8; ++i) part[wq][jl][bh * 8 + i] = acc[i];
    __syncthreads();
    for (int o = tid; o < 512; o += 256) {
      int jj = o >> 4, bb = o & 15;
      float s = part[0][jj][bb] + part[1][jj][bb] + part[2][jj][bb] + part[3][jj][bb];
      linh[(size_t)bb * 512 + idx * 32 + jj] = s + whb[idx * 32 + jj];
    }
  }
}

// ---------- tail: logits for t=127 ----------
__global__ __launch_bounds__(256) void k_log_tail(
    const float* __restrict__ okT, const float* __restrict__ woutT,
    const float* __restrict__ woutb, float* __restrict__ ev, float* __restrict__ evp) {
  int lane = threadIdx.x & 63, wq = threadIdx.x >> 6;
  logits_block(blockIdx.x, lane, wq, okT, woutT, woutb, ev, evp);
}

__global__ void k_norm(const float* __restrict__ ev, const float* __restrict__ evp,
                       float* __restrict__ outp, int t) {
  norm_block(blockIdx.x, threadIdx.x, ev, evp, outp, t);
}

__global__ void k_argmax(const float* __restrict__ outp, float* __restrict__ tgt) {
  int bt = blockIdx.x;
  int lane = threadIdx.x;
  const float* row = outp + (size_t)bt * NV;
  float bv = -1.f;
  int bi = 0;
  for (int v = lane; v < NV; v += 64) {
    float x = row[v];
    if (x > bv) { bv = x; bi = v; }
  }
#pragma unroll
  for (int m = 1; m < 64; m <<= 1) {
    float ov = __shfl_xor(bv, m, 64);
    int oi = __shfl_xor(bi, m, 64);
    if (ov > bv || (ov == bv && oi < bi)) { bv = ov; bi = oi; }
  }
  if (lane == 0) tgt[bt] = (float)bi;
}

extern "C" void kernel_launch(void* const* d_in, const int* in_sizes, int n_in,
                              void* d_out, int out_size, void* d_ws, size_t ws_size,
                              hipStream_t stream) {
  (void)in_sizes; (void)n_in; (void)out_size;
  if (ws_size < WS_FLOATS * sizeof(float)) return;

  const float* feat     = (const float*)d_in[0];
  const int*   formulas = (const int*)d_in[1];
  const float* Wih_f    = (const float*)d_in[2];
  const float* Whh_f    = (const float*)d_in[3];
  const float* bih_f    = (const float*)d_in[4];
  const float* bhh_f    = (const float*)d_in[5];
  const float* Wih_b    = (const float*)d_in[6];
  const float* Whh_b    = (const float*)d_in[7];
  const float* bih_b    = (const float*)d_in[8];
  const float* bhh_b    = (const float*)d_in[9];
  const float* emb      = (const float*)d_in[10];
  const float* Wc_w     = (const float*)d_in[11];
  const float* Wc_b     = (const float*)d_in[12];
  const float* Wout_w   = (const float*)d_in[13];
  const float* Wout_b   = (const float*)d_in[14];
  const float* Vh0      = (const float*)d_in[15];
  const float* Vc0      = (const float*)d_in[16];
  const float* beta     = (const float*)d_in[17];
  const float* Wh_w     = (const float*)d_in[18];
  const float* Wh_b     = (const float*)d_in[19];
  const float* Wv_w     = (const float*)d_in[20];
  const float* Wv_b     = (const float*)d_in[21];
  const float* Wdec_ih  = (const float*)d_in[22];
  const float* Wdec_hh  = (const float*)d_in[23];
  const float* bdec_ih  = (const float*)d_in[24];
  const float* bdec_hh  = (const float*)d_in[25];

  float* ws = (float*)d_ws;
  float* xpreF  = ws + OFF_XPRE_F;
  float* xpreB  = ws + OFF_XPRE_B;
  float* xt     = ws + OFF_XT;
  float* encout = ws + OFF_ENC;
  float* wenc   = ws + OFF_WENC;
  float* wdT    = ws + OFF_WDT;
  float* whT    = ws + OFF_WHT;
  float* wcT    = ws + OFF_WCT;
  float* woutT  = ws + OFF_WOUTT;
  float* hA     = ws + OFF_HA;
  float* hB     = ws + OFF_HB;
  float* cenc   = ws + OFF_CENC;
  float* cdec   = ws + OFF_CDEC;
  float* ctx0   = ws + OFF_CTX0;
  float* okT    = ws + OFF_OKT;
  float* octT   = ws + OFF_OCTT;
  // decoder scratch aliased into xpreB (free after encoder)
  float* gpart  = xpreB;                 // 12*16*2048 = 393216
  float* ctxp   = gpart + 393216;        // 16*16*512  = 131072
  float* spart  = ctxp + 131072;         // 256
  float* ev     = spart + 256;           // 16*600
  float* evp    = ev + 9600;             // 256
  float* linh   = evp + 256;             // 16*512
  float* embproj = xpreF;                // alias (free after encoder)
  float* wvenc   = xt;                   // alias (free after input GEMMs)

  float* out_logits = (float*)d_out;
  float* out_tgt    = out_logits + (size_t)NB * NT * NV;

  // ---- prep ----
  k_transpose<<<(2048 * 336 + 255) / 256, 256, 0, stream>>>(wdT, Wdec_ih, 2048, 336);
  k_transpose<<<(2048 * 512 + 255) / 256, 256, 0, stream>>>(wdT + 336 * 2048, Wdec_hh, 2048, 512);
  k_transpose<<<(512 * 512 + 255) / 256, 256, 0, stream>>>(whT, Wh_w, 512, 512);
  k_transpose<<<(256 * 1024 + 255) / 256, 256, 0, stream>>>(wcT, Wc_w, 256, 1024);
  k_transpose<<<(600 * 256 + 255) / 256, 256, 0, stream>>>(woutT, Wout_w, 600, 256);
  k_prep_wenc<<<1024, 256, 0, stream>>>(wenc, Whh_f, 0);
  k_prep_wenc<<<1024, 256, 0, stream>>>(wenc, Whh_b, 1);
  k_buildXt<<<dim3(256, 8), 256, 0, stream>>>(xt, feat);
  k_gemm_nt<<<dim3(128, 8), 256, 0, stream>>>(xt, Wih_f, bih_f, bhh_f, xpreF, 16384, 1024, 512);
  k_gemm_nt<<<dim3(128, 8), 256, 0, stream>>>(xt, Wih_b, bih_b, bhh_b, xpreB, 16384, 1024, 512);

  // ---- encoder ----
  k_enc_init<<<512, 256, 0, stream>>>(hA, cenc, Vh0, Vc0);
  for (int t = 0; t < 64; ++t) {
    const float* hp = (t & 1) ? hB : hA;
    float* hn = (t & 1) ? hA : hB;
    k_enc_step<<<dim3(32, 4, 2), 256, 0, stream>>>(hp, hn, cenc, wenc, xpreF, xpreB, encout, t);
  }
  k_gemm_nt<<<dim3(128, 4), 256, 0, stream>>>(encout, Wv_w, Wv_b, nullptr, wvenc, 16384, 512, 512);
  k_conv<<<16, 256, 0, stream>>>(hA, cenc, encout, cdec, okT, ctx0);
  k_O0v2<<<16, 256, 0, stream>>>(okT, ctx0, wcT, Wc_b, whT, Wh_b, okT, linh);
  k_embproj<<<dim3(8, 2048), 256, 0, stream>>>(formulas, emb, wdT, bdec_ih, bdec_hh, embproj);

  // ---- decoder: 3 kernels per step ----
  for (int t = 0; t < NT; ++t) {
    k_dec1<<<256, 256, 0, stream>>>(okT, wdT, woutT, Wout_b, linh, beta, wvenc, encout,
                                    gpart, ctxp, spart, ev, evp, t);
    k_dec2a<<<16, 256, 0, stream>>>(gpart, embproj, ctxp, spart, ev, evp,
                                    cdec, okT, octT, out_logits, t);
    k_dec2b<<<24, 256, 0, stream>>>(octT, wcT, Wc_b, whT, Wh_b, okT, linh);
  }
  // ---- tail ----
  k_log_tail<<<10, 256, 0, stream>>>(okT, woutT, Wout_b, ev, evp);
  k_norm<<<16, 256, 0, stream>>>(ev, evp, out_logits, NT - 1);
  k_argmax<<<NB * NT, 64, 0, stream>>>(out_logits, out_tgt);
}